// Round 3
// baseline (679.035 us; speedup 1.0000x reference)
//
#include <hip/hip_runtime.h>
#include <hip/hip_bf16.h>
#include <stdint.h>

typedef unsigned short u16;
typedef __attribute__((ext_vector_type(8))) __bf16 bf16x8;
typedef __attribute__((ext_vector_type(4))) float f32x4;

#define BATCH 8192
#define HID   2048
#define COMB  4096
#define NT    64   // K tiles of 64 (even => last tile parity 1)

__device__ __forceinline__ u16 f2bf(float f) {
  uint32_t u = __float_as_uint(f);
  u += 0x7fffu + ((u >> 16) & 1u);
  return (u16)(u >> 16);
}
__device__ __forceinline__ float bf2f(u16 b) {
  return __uint_as_float(((uint32_t)b) << 16);
}
__device__ __forceinline__ float fsigmoid(float x) { return 1.0f / (1.0f + __expf(-x)); }
__device__ __forceinline__ float ftanh(float x) { return 1.0f - 2.0f / (__expf(2.0f * x) + 1.0f); }

__device__ __forceinline__ void gload_lds16(const void* g, void* l) {
  __builtin_amdgcn_global_load_lds(
      (__attribute__((address_space(1))) void*)(uintptr_t)g,
      (__attribute__((address_space(3))) void*)(uintptr_t)l,
      16, 0, 0);
}

#define BARRIER() do { asm volatile("" ::: "memory"); __builtin_amdgcn_s_barrier(); asm volatile("" ::: "memory"); } while (0)
#define LGKM8()   asm volatile("s_waitcnt lgkmcnt(8)" ::: "memory")
#define VMCNT2()  asm volatile("s_waitcnt vmcnt(2)" ::: "memory")
#define VMCNT0()  asm volatile("s_waitcnt vmcnt(0)" ::: "memory")
#define VMCNT6()  asm volatile("s_waitcnt vmcnt(6)" ::: "memory")

// Stage one 128x64 bf16 half-tile: linear LDS dest, inverse-XOR-swizzled global src.
// LDS(row, granule g) = global(row, g ^ (row&7)); granule = 16B.
__device__ __forceinline__ void stage_half(const u16* __restrict__ src, size_t ld,
                                           char* ldsHalf, int w, int l) {
  const int lrow = l >> 3;
  const int g    = (l & 7) ^ (lrow & 7);
#pragma unroll
  for (int i = 0; i < 2; ++i) {
    const int r0 = (w * 2 + i) * 8;
    gload_lds16(src + (size_t)(r0 + lrow) * ld + g * 8, ldsHalf + r0 * 128);
  }
}

// Fragment read (swizzled): byte = row*128 + ((gran ^ (lr&7))<<4), row = idx*16+lr (+bro for B)
#define RDA(base, m, ks) (*(const bf16x8*)((base) + ((ks) ? loff1 : loff0) + (m) * 2048))
#define RDB(base, n, ks) (*(const bf16x8*)((base) + ((ks) ? loff1 : loff0) + (n) * 2048))

#define MFMA_HALF(AF, BB, MH, NH)                                                     \
  { _Pragma("unroll") for (int m_ = 0; m_ < 4; ++m_) {                                \
      _Pragma("unroll") for (int n_ = 0; n_ < 2; ++n_) {                              \
        _Pragma("unroll") for (int k_ = 0; k_ < 2; ++k_) {                            \
          acc[(MH) * 4 + m_][(NH) * 2 + n_] = __builtin_amdgcn_mfma_f32_16x16x32_bf16(\
              AF[m_][k_], BB[n_][k_], acc[(MH) * 4 + m_][(NH) * 2 + n_], 0, 0, 0);    \
        } } } }

// ---- pack [x | h_prev] f32 -> A1 bf16 [8192][4096] ----
__global__ void pack_A_kernel(const float* __restrict__ x, const float* __restrict__ h,
                              u16* __restrict__ A1) {
  const size_t tid = (size_t)blockIdx.x * blockDim.x + threadIdx.x;
  const int r  = (int)(tid >> 9);
  const int c8 = (int)(tid & 511);
  const float* s = (c8 < 256) ? (x + (size_t)r * 2048 + (size_t)c8 * 8)
                              : (h + (size_t)r * 2048 + (size_t)(c8 - 256) * 8);
  const float4 v0 = ((const float4*)s)[0];
  const float4 v1 = ((const float4*)s)[1];
  const uint32_t p0 = (uint32_t)f2bf(v0.x) | ((uint32_t)f2bf(v0.y) << 16);
  const uint32_t p1 = (uint32_t)f2bf(v0.z) | ((uint32_t)f2bf(v0.w) << 16);
  const uint32_t p2 = (uint32_t)f2bf(v1.x) | ((uint32_t)f2bf(v1.y) << 16);
  const uint32_t p3 = (uint32_t)f2bf(v1.z) | ((uint32_t)f2bf(v1.w) << 16);
  *(uint4*)(A1 + tid * 8) = make_uint4(p0, p1, p2, p3);
}

// ---- transpose W [4096][2048] f32 -> dst [2048][4096] bf16 ----
__global__ void transpose_w_kernel(const float* __restrict__ src, u16* __restrict__ dst) {
  __shared__ float tile[32][33];
  const int n0 = blockIdx.x * 32;
  const int k0 = blockIdx.y * 32;
  const int tx = threadIdx.x, ty = threadIdx.y;
#pragma unroll
  for (int i = 0; i < 32; i += 8)
    tile[ty + i][tx] = src[(size_t)(k0 + ty + i) * 2048 + n0 + tx];
  __syncthreads();
#pragma unroll
  for (int i = 0; i < 32; i += 8)
    dst[(size_t)(n0 + ty + i) * 4096 + k0 + tx] = f2bf(tile[tx][ty + i]);
}

// ---- 256x256x64 pipelined 8-phase GEMM. MODE 0: z|r gates; MODE 1: n gate ----
template <int MODE>
__global__ __launch_bounds__(512, 2) void gemm8p_kernel(
    const u16* __restrict__ A1, const u16* __restrict__ RH,
    const u16* __restrict__ Bt, const float* __restrict__ h_prev,
    const float* __restrict__ bias0, const float* __restrict__ bias1,
    u16* __restrict__ Z, u16* __restrict__ RHout, float* __restrict__ out) {
  extern __shared__ char smem[];   // [0,64K): A slots (parity*2+half)<<14 ; [64K,128K): B slots
  constexpr int NBN = (MODE == 0) ? 16 : 8;

  const int t = threadIdx.x;
  const int l = t & 63, w = t >> 6;
  const int wm = w >> 2, wn = w & 3;
  const int lr = l & 15, khi = l >> 4;

  const int nwg = 32 * NBN;
  int bid = blockIdx.x;
  bid = (bid & 7) * (nwg >> 3) + (bid >> 3);
  const int bm = bid / NBN, bn = bid % NBN;
  const int arow = bm * 256;
  const int brow = bn * 256;

  char* Abase = smem;
  char* Bbase = smem + 65536;

  auto stageA = [&](int T, int half) {
    const u16* src;
    size_t ld;
    if constexpr (MODE == 1) {
      if (T >= 32) { src = RH + (size_t)(arow + half * 128) * HID + (T * 64 - 2048); ld = HID; }
      else         { src = A1 + (size_t)(arow + half * 128) * COMB + T * 64;         ld = COMB; }
    } else {
      src = A1 + (size_t)(arow + half * 128) * COMB + T * 64; ld = COMB;
    }
    stage_half(src, ld, Abase + (((T & 1) * 2 + half) << 14), w, l);
  };
  auto stageB = [&](int T, int half) {
    stage_half(Bt + (size_t)(brow + half * 128) * COMB + T * 64, COMB,
               Bbase + (((T & 1) * 2 + half) << 14), w, l);
  };

  // Lane-constant read bases. row&7 == lr&7 for all fragment rows (offsets are mult of 16).
  const int loff0 = lr * 128 + (((khi)     ^ (lr & 7)) << 4);
  const int loff1 = lr * 128 + (((4 + khi) ^ (lr & 7)) << 4);
  const char* A0p = Abase + ((0 * 2 + wm) << 14);
  const char* A1p = Abase + ((1 * 2 + wm) << 14);
  const char* B0p = Bbase + ((0 * 2 + (wn >> 1)) << 14) + (wn & 1) * 64 * 128;
  const char* B1p = Bbase + ((1 * 2 + (wn >> 1)) << 14) + (wn & 1) * 64 * 128;

  // Prologue staging: tile0 all 4 halves, then B0(1),B1(1),A0(1).
  stageA(0, 0); stageA(0, 1); stageB(0, 0); stageB(0, 1);
  stageB(1, 0); stageB(1, 1); stageA(1, 0);
  VMCNT6();          // drain tile 0; leave {B0(1),B1(1),A0(1)} in flight
  BARRIER();

  f32x4 acc[8][4] = {};
  bf16x8 af_lo[4][2], af_hi[4][2], bb_lo[2][2], bb_hi[2][2];

  // Prologue reads (tile 0, parity 0): afLo, bbHi, bbLo (bbHi before bbLo).
#pragma unroll
  for (int m = 0; m < 4; ++m) { af_lo[m][0] = RDA(A0p, m, 0); af_lo[m][1] = RDA(A0p, m, 1); }
#pragma unroll
  for (int n = 0; n < 2; ++n) { bb_hi[n][0] = RDB(B0p, n + 2, 0); bb_hi[n][1] = RDB(B0p, n + 2, 1); }
#pragma unroll
  for (int n = 0; n < 2; ++n) { bb_lo[n][0] = RDB(B0p, n, 0); bb_lo[n][1] = RDB(B0p, n, 1); }

#pragma unroll 2
  for (int j = 0; j < NT - 1; ++j) {
    const bool odd = j & 1;
    const char* Acur = odd ? A1p : A0p;
    const char* Anxt = odd ? A0p : A1p;
    const char* Bnxt = odd ? B0p : B1p;

    // R0: stage A1(j+1)
    stageA(j + 1, 1);
    BARRIER();
    // C0: read afHi(j); MFMA Q(0,0); certify B-parity(j) free (lgkmcnt(8) leaves only afHi)
#pragma unroll
    for (int m = 0; m < 4; ++m) { af_hi[m][0] = RDA(Acur, m + 4, 0); af_hi[m][1] = RDA(Acur, m + 4, 1); }
    __builtin_amdgcn_s_setprio(1);
    MFMA_HALF(af_lo, bb_lo, 0, 0);
    __builtin_amdgcn_s_setprio(0);
    LGKM8();
    BARRIER();

    // R1: stage B0(j+2) (B-parity(j) slot, certified by C0-end barrier)
    if (j < NT - 2) stageB(j + 2, 0);
    BARRIER();
    // C1: MFMA Q(0,1)
    __builtin_amdgcn_s_setprio(1);
    MFMA_HALF(af_lo, bb_hi, 0, 1);
    __builtin_amdgcn_s_setprio(0);
    BARRIER();

    // R2: counted vmcnt drains tile j+1 halves (leaves B0(j+2)); stage B1(j+2)
    if (j < NT - 2) { VMCNT2(); stageB(j + 2, 1); } else { VMCNT0(); }
    BARRIER();
    // C2: read afLo(j+1) (certified above); MFMA Q(1,1)
#pragma unroll
    for (int m = 0; m < 4; ++m) { af_lo[m][0] = RDA(Anxt, m, 0); af_lo[m][1] = RDA(Anxt, m, 1); }
    __builtin_amdgcn_s_setprio(1);
    MFMA_HALF(af_hi, bb_hi, 1, 1);
    __builtin_amdgcn_s_setprio(0);
    BARRIER();

    // R3: stage A0(j+2) (A-parity(j) slot, certified by C2-end barrier)
    if (j < NT - 2) stageA(j + 2, 0);
    BARRIER();
    // C3: read bbHi(j+1); MFMA Q(1,0); read bbLo(j+1) after (WAR on bb_lo)
#pragma unroll
    for (int n = 0; n < 2; ++n) { bb_hi[n][0] = RDB(Bnxt, n + 2, 0); bb_hi[n][1] = RDB(Bnxt, n + 2, 1); }
    __builtin_amdgcn_s_setprio(1);
    MFMA_HALF(af_hi, bb_lo, 1, 0);
    __builtin_amdgcn_s_setprio(0);
#pragma unroll
    for (int n = 0; n < 2; ++n) { bb_lo[n][0] = RDB(Bnxt, n, 0); bb_lo[n][1] = RDB(Bnxt, n, 1); }
    BARRIER();
  }

  // Tail tile NT-1 (parity 1): afLo/bbHi/bbLo already read; read afHi, 4 MFMA quads.
#pragma unroll
  for (int m = 0; m < 4; ++m) { af_hi[m][0] = RDA(A1p, m + 4, 0); af_hi[m][1] = RDA(A1p, m + 4, 1); }
  MFMA_HALF(af_lo, bb_lo, 0, 0);
  MFMA_HALF(af_lo, bb_hi, 0, 1);
  MFMA_HALF(af_hi, bb_hi, 1, 1);
  MFMA_HALF(af_hi, bb_lo, 1, 0);

  // ---- epilogue
  const int r0g = arow + wm * 128 + khi * 4;
  const int c0g = brow + wn * 64 + lr;
  if constexpr (MODE == 0) {
    const bool isZ = (bn < 8);
    const float* bias = isZ ? bias0 : bias1;
#pragma unroll
    for (int n = 0; n < 4; ++n) {
      const int colg = c0g + n * 16;
      const int col = isZ ? colg : (colg - 2048);
      const float bv = bias[col];
#pragma unroll
      for (int m = 0; m < 8; ++m)
#pragma unroll
        for (int r = 0; r < 4; ++r) {
          const int row = r0g + m * 16 + r;
          const size_t idx = (size_t)row * HID + col;
          const float v = acc[m][n][r] + bv;
          if (isZ) {
            Z[idx] = f2bf(fsigmoid(v));
          } else {
            const float rv = fsigmoid(v);
            RHout[idx] = f2bf(rv * h_prev[idx]);
          }
        }
    }
  } else {
#pragma unroll
    for (int n = 0; n < 4; ++n) {
      const int col = c0g + n * 16;
      const float bv = bias0[col];
#pragma unroll
      for (int m = 0; m < 8; ++m)
#pragma unroll
        for (int r = 0; r < 4; ++r) {
          const int row = r0g + m * 16 + r;
          const size_t idx = (size_t)row * HID + col;
          const float nn = ftanh(acc[m][n][r] + bv);
          const float zz = bf2f(Z[idx]);
          const float hp = h_prev[idx];
          out[idx] = (1.0f - zz) * hp + zz * nn;
        }
    }
  }
}

extern "C" void kernel_launch(void* const* d_in, const int* in_sizes, int n_in,
                              void* d_out, int out_size, void* d_ws, size_t ws_size,
                              hipStream_t stream) {
  const float* x  = (const float*)d_in[0];
  const float* h  = (const float*)d_in[1];
  const float* Wz = (const float*)d_in[2];
  const float* bz = (const float*)d_in[3];
  const float* Wr = (const float*)d_in[4];
  const float* br = (const float*)d_in[5];
  const float* Wn = (const float*)d_in[6];
  const float* bn = (const float*)d_in[7];
  float* out = (float*)d_out;

  char* ws = (char*)d_ws;
  u16* A1  = (u16*)(ws);                    // 8192*4096*2 = 67108864
  u16* RH  = (u16*)(ws + 67108864);         // 8192*2048*2 = 33554432
  u16* B1t = (u16*)(ws + 100663296);        // 4096*4096*2 = 33554432  ([Wz;Wr]^T)
  u16* B2t = (u16*)(ws + 134217728);        // 2048*4096*2 = 16777216  (Wn^T)
  u16* Z   = (u16*)(ws + 150994944);        // 8192*2048*2 = 33554432

  (void)hipFuncSetAttribute(reinterpret_cast<const void*>(&gemm8p_kernel<0>),
                            hipFuncAttributeMaxDynamicSharedMemorySize, 131072);
  (void)hipFuncSetAttribute(reinterpret_cast<const void*>(&gemm8p_kernel<1>),
                            hipFuncAttributeMaxDynamicSharedMemorySize, 131072);

  pack_A_kernel<<<16384, 256, 0, stream>>>(x, h, A1);
  dim3 tb(32, 8);
  transpose_w_kernel<<<dim3(64, 128), tb, 0, stream>>>(Wz, B1t);
  transpose_w_kernel<<<dim3(64, 128), tb, 0, stream>>>(Wr, B1t + (size_t)2048 * 4096);
  transpose_w_kernel<<<dim3(64, 128), tb, 0, stream>>>(Wn, B2t);

  gemm8p_kernel<0><<<dim3(512), 512, 131072, stream>>>(A1, nullptr, B1t, h, bz, br, Z, RH, nullptr);
  gemm8p_kernel<1><<<dim3(256), 512, 131072, stream>>>(A1, RH, B2t, h, bn, nullptr, Z, nullptr, out);
}

// Round 4
// 579.447 us; speedup vs baseline: 1.1719x; 1.1719x over previous
//
#include <hip/hip_runtime.h>
#include <hip/hip_bf16.h>
#include <stdint.h>

typedef unsigned short u16;
typedef __attribute__((ext_vector_type(8))) __bf16 bf16x8;
typedef __attribute__((ext_vector_type(4))) float f32x4;

#define BATCH 8192
#define HID   2048
#define COMB  4096
#define NT    64   // K tiles of 64

__device__ __forceinline__ u16 f2bf(float f) {
  uint32_t u = __float_as_uint(f);
  u += 0x7fffu + ((u >> 16) & 1u);
  return (u16)(u >> 16);
}
__device__ __forceinline__ float bf2f(u16 b) {
  return __uint_as_float(((uint32_t)b) << 16);
}
__device__ __forceinline__ float fsigmoid(float x) { return 1.0f / (1.0f + __expf(-x)); }
__device__ __forceinline__ float ftanh(float x) { return 1.0f - 2.0f / (__expf(2.0f * x) + 1.0f); }

__device__ __forceinline__ void gload_lds16(const void* g, void* l) {
  __builtin_amdgcn_global_load_lds(
      (__attribute__((address_space(1))) void*)(uintptr_t)g,
      (__attribute__((address_space(3))) void*)(uintptr_t)l,
      16, 0, 0);
}

#define BARRIER() do { asm volatile("" ::: "memory"); __builtin_amdgcn_s_barrier(); asm volatile("" ::: "memory"); } while (0)
#define LGKM0()   asm volatile("s_waitcnt lgkmcnt(0)" ::: "memory")
#define LGKM8()   asm volatile("s_waitcnt lgkmcnt(8)" ::: "memory")
#define VM6()     asm volatile("s_waitcnt vmcnt(6)" ::: "memory")
#define VM0()     asm volatile("s_waitcnt vmcnt(0)" ::: "memory")

// Stage one 128x64 bf16 half-tile (2 gloads/wave): linear LDS dest,
// inverse-XOR-swizzled global src. LDS(row, g16) = global(row, g16 ^ (row&7)).
__device__ __forceinline__ void stage_half(const u16* __restrict__ src, size_t ld,
                                           char* ldsHalf, int w, int l) {
  const int lrow = l >> 3;
  const int g    = (l & 7) ^ (lrow & 7);
#pragma unroll
  for (int i = 0; i < 2; ++i) {
    const int r0 = (w * 2 + i) * 8;
    gload_lds16(src + (size_t)(r0 + lrow) * ld + g * 8, ldsHalf + r0 * 128);
  }
}

// Stage one 64-row quarter of a 128-row half slot (1 gload/wave). q in {0,1}.
__device__ __forceinline__ void stage_q(const u16* __restrict__ src, size_t ld,
                                        char* ldsHalf, int q, int w, int l) {
  const int lrow = l >> 3;
  const int g    = (l & 7) ^ (lrow & 7);
  const int r0   = q * 64 + w * 8;
  gload_lds16(src + (size_t)(r0 + lrow) * ld + g * 8, ldsHalf + r0 * 128);
}

#define MFMA_QUAD(MH, NH)                                                          \
  {                                                                                \
    _Pragma("unroll") for (int m_ = 0; m_ < 4; ++m_) {                             \
      _Pragma("unroll") for (int n_ = 0; n_ < 2; ++n_) {                           \
        _Pragma("unroll") for (int ks_ = 0; ks_ < 2; ++ks_) {                      \
          acc[(MH)*4 + m_][(NH)*2 + n_] = __builtin_amdgcn_mfma_f32_16x16x32_bf16( \
              af[(MH)*4 + m_][ks_], bb[(NH)*2 + n_][ks_],                          \
              acc[(MH)*4 + m_][(NH)*2 + n_], 0, 0, 0);                             \
        } } }                                                                      \
  }

// ---- pack [x | h_prev] f32 -> A1 bf16 [8192][4096] ----
__global__ void pack_A_kernel(const float* __restrict__ x, const float* __restrict__ h,
                              u16* __restrict__ A1) {
  const size_t tid = (size_t)blockIdx.x * blockDim.x + threadIdx.x;
  const int r  = (int)(tid >> 9);
  const int c8 = (int)(tid & 511);
  const float* s = (c8 < 256) ? (x + (size_t)r * 2048 + (size_t)c8 * 8)
                              : (h + (size_t)r * 2048 + (size_t)(c8 - 256) * 8);
  const float4 v0 = ((const float4*)s)[0];
  const float4 v1 = ((const float4*)s)[1];
  const uint32_t p0 = (uint32_t)f2bf(v0.x) | ((uint32_t)f2bf(v0.y) << 16);
  const uint32_t p1 = (uint32_t)f2bf(v0.z) | ((uint32_t)f2bf(v0.w) << 16);
  const uint32_t p2 = (uint32_t)f2bf(v1.x) | ((uint32_t)f2bf(v1.y) << 16);
  const uint32_t p3 = (uint32_t)f2bf(v1.z) | ((uint32_t)f2bf(v1.w) << 16);
  *(uint4*)(A1 + tid * 8) = make_uint4(p0, p1, p2, p3);
}

// ---- transpose W [4096][2048] f32 -> dst [2048][4096] bf16 ----
__global__ void transpose_w_kernel(const float* __restrict__ src, u16* __restrict__ dst) {
  __shared__ float tile[32][33];
  const int n0 = blockIdx.x * 32;
  const int k0 = blockIdx.y * 32;
  const int tx = threadIdx.x, ty = threadIdx.y;
#pragma unroll
  for (int i = 0; i < 32; i += 8)
    tile[ty + i][tx] = src[(size_t)(k0 + ty + i) * 2048 + n0 + tx];
  __syncthreads();
#pragma unroll
  for (int i = 0; i < 32; i += 8)
    dst[(size_t)(n0 + ty + i) * 4096 + k0 + tx] = f2bf(tile[tx][ty + i]);
}

// ---- 256x256x64 8-phase GEMM, reads spread 12/8/4/0. MODE 0: z|r; MODE 1: n ----
template <int MODE>
__global__ __launch_bounds__(512, 2) void gemm8p_kernel(
    const u16* __restrict__ A1, const u16* __restrict__ RH,
    const u16* __restrict__ Bt, const float* __restrict__ h_prev,
    const float* __restrict__ bias0, const float* __restrict__ bias1,
    u16* __restrict__ Z, u16* __restrict__ RHout, float* __restrict__ out) {
  extern __shared__ char smem[];   // [0,64K): A slots (parity*2+half)<<14 ; [64K,128K): B slots
  constexpr int NBN = (MODE == 0) ? 16 : 8;

  const int t = threadIdx.x;
  const int l = t & 63, w = t >> 6;
  const int wm = w >> 2, wn = w & 3;
  const int lr = l & 15, khi = l >> 4;

  const int nwg = 32 * NBN;
  int bid = blockIdx.x;
  bid = (bid & 7) * (nwg >> 3) + (bid >> 3);
  const int bm = bid / NBN, bn = bid % NBN;
  const int arow = bm * 256;
  const int brow = bn * 256;

  char* Abase = smem;
  char* Bbase = smem + 65536;

  auto asrc = [&](int T, int half) -> const u16* {
    if constexpr (MODE == 1) {
      if (T >= 32) return RH + (size_t)(arow + half * 128) * HID + (T * 64 - 2048);
    }
    return A1 + (size_t)(arow + half * 128) * COMB + T * 64;
  };
  auto ald = [&](int T) -> size_t {
    if constexpr (MODE == 1) { if (T >= 32) return HID; }
    return COMB;
  };
  auto stageAq = [&](int T, int half, int q) {
    stage_q(asrc(T, half), ald(T), Abase + (((T & 1) * 2 + half) << 14), q, w, l);
  };
  auto stageB = [&](int T, int half) {
    stage_half(Bt + (size_t)(brow + half * 128) * COMB + T * 64, COMB,
               Bbase + (((T & 1) * 2 + half) << 14), w, l);
  };

  // Lane-constant swizzled read offsets (row&7 == lr&7 for all fragment rows).
  const int loff0 = lr * 128 + ((khi       ^ (lr & 7)) << 4);
  const int loff1 = lr * 128 + (((4 + khi) ^ (lr & 7)) << 4);

  // Prologue: tile0 {A q0,q1 both halves; B0; B1} + tile1 {A all quarters; B0}.
  stageAq(0, 0, 0); stageAq(0, 1, 0); stageAq(0, 0, 1); stageAq(0, 1, 1);
  stageB(0, 0); stageB(0, 1);
  stageAq(1, 0, 0); stageAq(1, 1, 0); stageAq(1, 0, 1); stageAq(1, 1, 1);
  stageB(1, 0);
  VM6();          // drain tile 0 (8 loads); leave {A(1) x4, B0(1) x2}
  BARRIER();

  f32x4 acc[8][4] = {};
  bf16x8 af[8][2], bb[4][2];

#pragma unroll 2
  for (int j = 0; j < NT; ++j) {
    const int p = j & 1;
    const char* Ah = Abase + (((p << 1) + wm) << 14);
    const char* Bh = Bbase + (((p << 1) + (wn >> 1)) << 14) + (wn & 1) * 64 * 128;

    // ---- ph0: read afLo(8) + bbLo(4); stage B1(j+1); lgkm8; Q(0,0)
#pragma unroll
    for (int m = 0; m < 4; ++m) {
      af[m][0] = *(const bf16x8*)(Ah + m * 2048 + loff0);
      af[m][1] = *(const bf16x8*)(Ah + m * 2048 + loff1);
    }
#pragma unroll
    for (int n = 0; n < 2; ++n) {
      bb[n][0] = *(const bf16x8*)(Bh + n * 2048 + loff0);
      bb[n][1] = *(const bf16x8*)(Bh + n * 2048 + loff1);
    }
    if (j < NT - 1) stageB(j + 1, 1);
    LGKM8();
    BARRIER();
    LGKM0();
    __builtin_amdgcn_s_setprio(1);
    MFMA_QUAD(0, 0);
    __builtin_amdgcn_s_setprio(0);
    BARRIER();

    // ---- ph1: read afHi(8); stage A(j+2) quarter0 of both halves; Q(1,0)
#pragma unroll
    for (int m = 4; m < 8; ++m) {
      af[m][0] = *(const bf16x8*)(Ah + m * 2048 + loff0);
      af[m][1] = *(const bf16x8*)(Ah + m * 2048 + loff1);
    }
    if (j < NT - 2) { stageAq(j + 2, 0, 0); stageAq(j + 2, 1, 0); }
    BARRIER();
    LGKM0();
    __builtin_amdgcn_s_setprio(1);
    MFMA_QUAD(1, 0);
    __builtin_amdgcn_s_setprio(0);
    BARRIER();

    // ---- ph2: read bbHi(4); stage A(j+2) quarter1 of both halves; Q(1,1)
#pragma unroll
    for (int n = 2; n < 4; ++n) {
      bb[n][0] = *(const bf16x8*)(Bh + n * 2048 + loff0);
      bb[n][1] = *(const bf16x8*)(Bh + n * 2048 + loff1);
    }
    if (j < NT - 2) { stageAq(j + 2, 0, 1); stageAq(j + 2, 1, 1); }
    BARRIER();
    LGKM0();
    __builtin_amdgcn_s_setprio(1);
    MFMA_QUAD(1, 1);
    __builtin_amdgcn_s_setprio(0);
    BARRIER();

    // ---- ph3: stage B0(j+2); Q(0,1); counted vmcnt at tile boundary
    if (j < NT - 2) stageB(j + 2, 0);
    BARRIER();
    __builtin_amdgcn_s_setprio(1);
    MFMA_QUAD(0, 1);
    __builtin_amdgcn_s_setprio(0);
    if (j < NT - 2) { VM6(); } else { VM0(); }
    BARRIER();
  }

  // ---- epilogue
  const int r0g = arow + wm * 128 + khi * 4;
  const int c0g = brow + wn * 64 + lr;
  if constexpr (MODE == 0) {
    const bool isZ = (bn < 8);
    const float* bias = isZ ? bias0 : bias1;
#pragma unroll
    for (int n = 0; n < 4; ++n) {
      const int colg = c0g + n * 16;
      const int col = isZ ? colg : (colg - 2048);
      const float bv = bias[col];
#pragma unroll
      for (int m = 0; m < 8; ++m)
#pragma unroll
        for (int r = 0; r < 4; ++r) {
          const int row = r0g + m * 16 + r;
          const size_t idx = (size_t)row * HID + col;
          const float v = acc[m][n][r] + bv;
          if (isZ) {
            Z[idx] = f2bf(fsigmoid(v));
          } else {
            const float rv = fsigmoid(v);
            RHout[idx] = f2bf(rv * h_prev[idx]);
          }
        }
    }
  } else {
#pragma unroll
    for (int n = 0; n < 4; ++n) {
      const int col = c0g + n * 16;
      const float bv = bias0[col];
#pragma unroll
      for (int m = 0; m < 8; ++m)
#pragma unroll
        for (int r = 0; r < 4; ++r) {
          const int row = r0g + m * 16 + r;
          const size_t idx = (size_t)row * HID + col;
          const float nn = ftanh(acc[m][n][r] + bv);
          const float zz = bf2f(Z[idx]);
          const float hp = h_prev[idx];
          out[idx] = (1.0f - zz) * hp + zz * nn;
        }
    }
  }
}

extern "C" void kernel_launch(void* const* d_in, const int* in_sizes, int n_in,
                              void* d_out, int out_size, void* d_ws, size_t ws_size,
                              hipStream_t stream) {
  const float* x  = (const float*)d_in[0];
  const float* h  = (const float*)d_in[1];
  const float* Wz = (const float*)d_in[2];
  const float* bz = (const float*)d_in[3];
  const float* Wr = (const float*)d_in[4];
  const float* br = (const float*)d_in[5];
  const float* Wn = (const float*)d_in[6];
  const float* bn = (const float*)d_in[7];
  float* out = (float*)d_out;

  char* ws = (char*)d_ws;
  u16* A1  = (u16*)(ws);                    // 8192*4096*2 = 67108864
  u16* RH  = (u16*)(ws + 67108864);         // 8192*2048*2 = 33554432
  u16* B1t = (u16*)(ws + 100663296);        // 4096*4096*2 = 33554432  ([Wz;Wr]^T)
  u16* B2t = (u16*)(ws + 134217728);        // 2048*4096*2 = 16777216  (Wn^T)
  u16* Z   = (u16*)(ws + 150994944);        // 8192*2048*2 = 33554432

  (void)hipFuncSetAttribute(reinterpret_cast<const void*>(&gemm8p_kernel<0>),
                            hipFuncAttributeMaxDynamicSharedMemorySize, 131072);
  (void)hipFuncSetAttribute(reinterpret_cast<const void*>(&gemm8p_kernel<1>),
                            hipFuncAttributeMaxDynamicSharedMemorySize, 131072);

  pack_A_kernel<<<16384, 256, 0, stream>>>(x, h, A1);
  dim3 tb(32, 8);
  transpose_w_kernel<<<dim3(64, 128), tb, 0, stream>>>(Wz, B1t);
  transpose_w_kernel<<<dim3(64, 128), tb, 0, stream>>>(Wr, B1t + (size_t)2048 * 4096);
  transpose_w_kernel<<<dim3(64, 128), tb, 0, stream>>>(Wn, B2t);

  gemm8p_kernel<0><<<dim3(512), 512, 131072, stream>>>(A1, nullptr, B1t, h, bz, br, Z, RH, nullptr);
  gemm8p_kernel<1><<<dim3(256), 512, 131072, stream>>>(A1, RH, B2t, h, bn, nullptr, Z, nullptr, out);
}